// Round 9
// baseline (181.043 us; speedup 1.0000x reference)
//
#include <hip/hip_runtime.h>
#include <cstdint>
#include <cstddef>

#define AS1 __attribute__((address_space(1)))
#define AS3 __attribute__((address_space(3)))

typedef __attribute__((ext_vector_type(4))) float f32x4;
typedef __attribute__((ext_vector_type(2))) float f32x2;
typedef __attribute__((ext_vector_type(8))) short bf16x8;   // 8 bf16 in 4 VGPRs
typedef unsigned short u16;
typedef unsigned int u32;

#define B_ 2
#define S_ 2048
#define E_ 1024
#define H_ 16
#define D_ 64
#define M_ 4096  /* B_*S_ */

__device__ __forceinline__ u16 f2bf(float f) {
  union { float f; u32 u; } v; v.f = f;
  u32 u = v.u;
  u32 r = (u + 0x7FFFu + ((u >> 16) & 1u)) >> 16;   // RNE
  return (u16)r;
}
__device__ __forceinline__ float bf2f(u16 h) {
  union { u32 u; float f; } v; v.u = ((u32)h) << 16;
  return v.f;
}

__device__ __forceinline__ void gl2lds16(const void* g, void* l) {
  __builtin_amdgcn_global_load_lds((const AS1 void*)g, (AS3 void*)l, 16, 0, 0);
}

// ---------------------------------------------------------------------------
// prep: fp32 -> bf16 conversions (x, Wq|Wk|Wv concat, Wo) + interleaved
// rope (cos,sin) float2 table
// ---------------------------------------------------------------------------
__global__ __launch_bounds__(256) void prep_kernel(
    const float* __restrict__ x, const float* __restrict__ wq,
    const float* __restrict__ wk, const float* __restrict__ wv,
    const float* __restrict__ wo,
    u16* __restrict__ xb, u16* __restrict__ wqkv, u16* __restrict__ wob,
    float* __restrict__ cstab)
{
  int idx = blockIdx.x * 256 + threadIdx.x;
  const int NX4 = (M_ * E_) / 4;          // 1048576 float4s of x
  const int NW4 = (E_ * E_) / 4;          // 262144 per weight
  const int CONV_TOTAL = NX4 + 4 * NW4;   // 2097152
  if (idx < CONV_TOTAL) {
    const float* src; u16* dst; int off;
    if (idx < NX4)                { src = x;  dst = xb;              off = idx; }
    else if (idx < NX4 + NW4)     { src = wq; dst = wqkv;            off = idx - NX4; }
    else if (idx < NX4 + 2 * NW4) { src = wk; dst = wqkv + E_ * E_;  off = idx - NX4 - NW4; }
    else if (idx < NX4 + 3 * NW4) { src = wv; dst = wqkv + 2 * E_ * E_; off = idx - NX4 - 2 * NW4; }
    else                          { src = wo; dst = wob;             off = idx - NX4 - 3 * NW4; }
    float4 v = reinterpret_cast<const float4*>(src)[off];
    ushort4 o;
    o.x = f2bf(v.x); o.y = f2bf(v.y); o.z = f2bf(v.z); o.w = f2bf(v.w);
    reinterpret_cast<ushort4*>(dst)[off] = o;
  } else if (idx < CONV_TOTAL + S_ * 32) {
    int e = idx - CONV_TOTAL;
    int s = e >> 5, i = e & 31;
    double invf = pow(10000.0, -(double)i / 32.0);
    double ang = (double)s * invf;
    cstab[e * 2]     = (float)cos(ang);
    cstab[e * 2 + 1] = (float)sin(ang);
  }
}

// ---------------------------------------------------------------------------
// QKV GEMM, 256x256 tile, BK=64, 8 waves (2M x 4N), 8-phase schedule
// (T2 swizzle + T3/T4 counted vmcnt + T5 setprio), K=1024 -> 8 iterations
// of 2 K-tiles. C[m,n] = sum_k A[m,k]*B[n,k]; A=[4096,1024], B=[3072,1024].
// Epilogue: in-register RoPE on Q,K + per-wave LDS transpose -> coalesced
// stores to [B,H,S,D]; V -> transposed [B,H,D,S] scatter.
// (measured r7: < 43 us, down from 49.5 at the 128x128 2-phase structure)
// ---------------------------------------------------------------------------
#define BARR  asm volatile("s_barrier" ::: "memory")
#define LGKM0 asm volatile("s_waitcnt lgkmcnt(0)" ::: "memory")
#define VMC6  asm volatile("s_waitcnt vmcnt(6)" ::: "memory")
#define VMC0  asm volatile("s_waitcnt vmcnt(0)" ::: "memory")

__global__ __launch_bounds__(512, 2) void gemm_qkv(
    const u16* __restrict__ A, const u16* __restrict__ Bm,
    u16* __restrict__ q_out, u16* __restrict__ k_out, u16* __restrict__ vt_out,
    const float* __restrict__ cstab)
{
  __shared__ __align__(16) u16 lds8[65536];   // 128 KiB
  const int tid = threadIdx.x;
  const int w = tid >> 6, l = tid & 63;
  const int lr = l & 15, lg = l >> 4;
  const int wm = w >> 2, wn = w & 3;

  // XCD-aware bijective swizzle: 192 blocks = 8 XCDs x 24
  int bid = blockIdx.x;
  int wg = (bid & 7) * 24 + (bid >> 3);
  int mt = wg / 12, nt = wg % 12;

  // staging constants: lane covers row rA(+16*j), 16B chunk (l&3), source
  // k-chunk pre-swizzled so a swizzled ds_read returns logical data.
  const int rA = w * 32 + (l >> 2);
  const int koff = ((l & 3) ^ ((l >> 3) & 3)) * 8;
  const u16* aSrc = A + (size_t)(mt * 256 + rA) * 1024 + koff;
  const u16* bSrc = Bm + (size_t)(nt * 256 + rA) * 1024 + koff;
  const int aswz = 16 * (lg ^ ((lr >> 1) & 3));   // read-side chunk swizzle

#define STG(isB, ks, bb, t) do { \
    const u16* s_ = ((isB) ? bSrc : aSrc) + (t) * 64 + (ks) * 32; \
    u16* d_ = &lds8[(((bb)*2 + (isB))*2 + (ks)) * 8192 + w * 1024]; \
    gl2lds16(s_, d_); \
    gl2lds16(s_ + 16 * 1024, d_ + 512); \
  } while (0)

#define LDA8(qm, ks, bb) do { \
    const char* sl_ = (const char*)lds8 + (((bb)*2)*2 + (ks)) * 16384; \
    _Pragma("unroll") for (int mf_ = 0; mf_ < 4; ++mf_) { \
      int row_ = wm * 128 + (qm) * 64 + mf_ * 16 + lr; \
      av[mf_] = *(const bf16x8*)(sl_ + row_ * 64 + aswz); \
    } } while (0)

#define LDB8(ks, bb) do { \
    const char* sl_ = (const char*)lds8 + (((bb)*2 + 1)*2 + (ks)) * 16384; \
    _Pragma("unroll") for (int nf_ = 0; nf_ < 4; ++nf_) { \
      int row_ = wn * 64 + nf_ * 16 + lr; \
      bv[nf_] = *(const bf16x8*)(sl_ + row_ * 64 + aswz); \
    } } while (0)

#define MMA16(qm) do { \
    __builtin_amdgcn_s_setprio(1); \
    _Pragma("unroll") for (int mf_ = 0; mf_ < 4; ++mf_) \
    _Pragma("unroll") for (int nf_ = 0; nf_ < 4; ++nf_) \
      acc[(qm)*4 + mf_][nf_] = __builtin_amdgcn_mfma_f32_16x16x32_bf16( \
          av[mf_], bv[nf_], acc[(qm)*4 + mf_][nf_], 0, 0, 0); \
    __builtin_amdgcn_s_setprio(0); \
  } while (0)

  f32x4 acc[8][4];
#pragma unroll
  for (int i = 0; i < 8; ++i)
#pragma unroll
    for (int j = 0; j < 4; ++j) acc[i][j] = (f32x4){0.f, 0.f, 0.f, 0.f};
  bf16x8 av[4], bv[4];

  // prologue: K-tile 0 fully + K-tile 1 minus A-K1 (staged at iter0 ph1)
  STG(0, 0, 0, 0); STG(1, 0, 0, 0); STG(0, 1, 0, 0); STG(1, 1, 0, 0);
  STG(1, 0, 1, 1); STG(0, 0, 1, 1); STG(1, 1, 1, 1);
  VMC6; BARR;

  for (int i = 0; i < 8; ++i) {
    // ph1: buf0 K0 qm0 (+B K0)
    LDA8(0, 0, 0); LDB8(0, 0);
    STG(0, 1, 1, 2 * i + 1);
    BARR; LGKM0; MMA16(0); BARR;
    // ph2: buf0 K0 qm1
    LDA8(1, 0, 0);
    if (i < 7) STG(1, 0, 0, 2 * i + 2);
    BARR; LGKM0; MMA16(1); BARR;
    // ph3: buf0 K1 qm0 (+B K1)
    LDA8(0, 1, 0); LDB8(1, 0);
    if (i < 7) STG(0, 0, 0, 2 * i + 2);
    BARR; LGKM0; MMA16(0); BARR;
    // ph4: buf0 K1 qm1
    LDA8(1, 1, 0);
    if (i < 7) STG(1, 1, 0, 2 * i + 2);
    BARR; LGKM0; MMA16(1);
    if (i < 7) { VMC6; } else { VMC0; }
    BARR;
    // ph5: buf1 K0 qm0 (+B K0)
    LDA8(0, 0, 1); LDB8(0, 1);
    if (i < 7) STG(0, 1, 0, 2 * i + 2);
    BARR; LGKM0; MMA16(0); BARR;
    // ph6: buf1 K0 qm1
    LDA8(1, 0, 1);
    if (i < 7) STG(1, 0, 1, 2 * i + 3);
    BARR; LGKM0; MMA16(1); BARR;
    // ph7: buf1 K1 qm0 (+B K1)
    LDA8(0, 1, 1); LDB8(1, 1);
    if (i < 7) STG(0, 0, 1, 2 * i + 3);
    BARR; LGKM0; MMA16(0); BARR;
    // ph8: buf1 K1 qm1
    LDA8(1, 1, 1);
    if (i < 7) STG(1, 1, 1, 2 * i + 3);
    BARR; LGKM0; MMA16(1);
    if (i < 7) VMC6;
    BARR;
  }
  __syncthreads();   // all staging landed (vmcnt(0) at last ph4); LDS reusable

  // ---- epilogue: wave spans rows [stile,+128), cols = one head of one wsel
  int n0 = nt * 256 + wn * 64;
  int wsel = n0 >> 10;
  int hh = (n0 >> 6) & 15;
  int stile = mt * 256 + wm * 128;
  int b = stile >> 11;
  int s0 = stile & 2047;

  if (wsel == 2) {
    // V: transposed scatter [B,H,D,S], ushort4 along s
#pragma unroll
    for (int mf = 0; mf < 8; ++mf) {
      int s = s0 + mf * 16 + lg * 4;
#pragma unroll
      for (int nf = 0; nf < 4; ++nf) {
        int d = nf * 16 + lr;
        ushort4 pk;
        pk.x = f2bf(acc[mf][nf][0]); pk.y = f2bf(acc[mf][nf][1]);
        pk.z = f2bf(acc[mf][nf][2]); pk.w = f2bf(acc[mf][nf][3]);
        *reinterpret_cast<ushort4*>(
            vt_out + ((size_t)(b * 16 + hh) * 64 + d) * 2048 + s) = pk;
      }
    }
  } else {
    // Q/K: RoPE in-register (pair nf, nf+2), per-wave LDS transpose tile
    u16* gout = (wsel == 0 ? q_out : k_out) +
                ((size_t)(b * 16 + hh) * 2048 + s0) * 64;
    u16* lt = &lds8[w * 4352];            // per-wave [64][68] u16
    const f32x2* cst = (const f32x2*)cstab;
#pragma unroll
    for (int P = 0; P < 2; ++P) {         // two 64-row passes
#pragma unroll
      for (int mf_ = 0; mf_ < 4; ++mf_) {
        int mf = P * 4 + mf_;
        int rl = mf_ * 16 + lg * 4;
#pragma unroll
        for (int rr = 0; rr < 4; ++rr) {
          int s = s0 + P * 64 + rl + rr;
#pragma unroll
          for (int nf_ = 0; nf_ < 2; ++nf_) {
            int ii = nf_ * 16 + lr;
            f32x2 cs = cst[s * 32 + ii];
            float a = acc[mf][nf_][rr], b2 = acc[mf][nf_ + 2][rr];
            lt[(rl + rr) * 68 + ii]      = f2bf(a * cs.x - b2 * cs.y);
            lt[(rl + rr) * 68 + 32 + ii] = f2bf(b2 * cs.x + a * cs.y);
          }
        }
      }
      LGKM0;                              // wave-local tile written
      {
        int trl = l >> 3, tcc = l & 7;
#pragma unroll
        for (int it = 0; it < 8; ++it) {
          int row = it * 8 + trl;
          bf16x8 v = *(const bf16x8*)(lt + row * 68 + tcc * 8);
          *(bf16x8*)(gout + (size_t)(P * 64 + row) * 64 + tcc * 8) = v;
        }
      }
      LGKM0;                              // reads done before pass-2 overwrite
    }
  }
#undef STG
#undef LDA8
#undef LDB8
#undef MMA16
}

// ---------------------------------------------------------------------------
// out-projection GEMM (m97 128x128 structure): C[m,n]=sum_k A[m,k]*B[n,k],
// A = attn-out bf16 [4096,1024], B = Wo bf16 [1024,1024], fp32 out.
// ---------------------------------------------------------------------------
__global__ __launch_bounds__(256) void gemm_out(
    const u16* __restrict__ A, const u16* __restrict__ Bm,
    float* __restrict__ f_out)
{
  __shared__ __align__(16) u16 smem[16384];
  u16* lA = smem;
  u16* lB = smem + 8192;
  const int tid = threadIdx.x;
  const int w = tid >> 6, l = tid & 63;
  const int lr = l & 15, lg = l >> 4;
  const int mt = blockIdx.y, nt = blockIdx.x;
  const int woffm = (w >> 1) * 64, woffn = (w & 1) * 64;

  const int srow = l >> 3;
  const int scol = ((l & 7) ^ srow) * 8;
  const u16* Abase = A + (size_t)(mt * 128) * 1024;
  const u16* Bbase = Bm + (size_t)(nt * 128) * 1024;

  f32x4 acc[4][4];
#pragma unroll
  for (int i = 0; i < 4; ++i)
#pragma unroll
    for (int j = 0; j < 4; ++j) acc[i][j] = (f32x4){0.f, 0.f, 0.f, 0.f};

  for (int kt = 0; kt < 1024; kt += 64) {
    __syncthreads();
#pragma unroll
    for (int i = 0; i < 4; ++i) {
      int ch = w * 4 + i;
      int row = ch * 8 + srow;
      gl2lds16(Abase + row * 1024 + kt + scol, &lA[ch * 512]);
      gl2lds16(Bbase + row * 1024 + kt + scol, &lB[ch * 512]);
    }
    __syncthreads();
#pragma unroll
    for (int kk = 0; kk < 2; ++kk) {
      bf16x8 av[4], bv[4];
#pragma unroll
      for (int mf = 0; mf < 4; ++mf) {
        int row = woffm + mf * 16 + lr;
        int byteoff = row * 128 + ((kk * 64 + lg * 16) ^ ((row & 7) << 4));
        av[mf] = *(const bf16x8*)((const char*)lA + byteoff);
      }
#pragma unroll
      for (int nf = 0; nf < 4; ++nf) {
        int row = woffn + nf * 16 + lr;
        int byteoff = row * 128 + ((kk * 64 + lg * 16) ^ ((row & 7) << 4));
        bv[nf] = *(const bf16x8*)((const char*)lB + byteoff);
      }
#pragma unroll
      for (int mf = 0; mf < 4; ++mf)
#pragma unroll
        for (int nf = 0; nf < 4; ++nf)
          acc[mf][nf] = __builtin_amdgcn_mfma_f32_16x16x32_bf16(
              av[mf], bv[nf], acc[mf][nf], 0, 0, 0);
    }
  }

#pragma unroll
  for (int mf = 0; mf < 4; ++mf) {
    int m = mt * 128 + woffm + mf * 16 + lg * 4;
#pragma unroll
    for (int nf = 0; nf < 4; ++nf) {
      int n = nt * 128 + woffn + nf * 16 + lr;
#pragma unroll
      for (int rr = 0; rr < 4; ++rr)
        f_out[(size_t)(m + rr) * 1024 + n] = acc[mf][nf][rr];
    }
  }
}

// ---------------------------------------------------------------------------
// Banded causal attention, window 256. One wave = 16 query rows (row = lr).
// SWAPPED QK^T (A=K, B=Q) with permuted K-rows so each lane's 8 score regs
// are exactly keys kt+lg*8+0..7 -> P stays IN REGISTER as the PV B-operand:
// no LDS, no fences, no per-tile shuffles. Softmax in-lane over 8 regs;
// defer-max (THR=8) reduces across the 4 lg-copies only when triggered.
// O accumulates transposed (col = s_q); ushort4 stores along d.
// ---------------------------------------------------------------------------
__global__ __launch_bounds__(256) void attn_kernel(
    const u16* __restrict__ qb, const u16* __restrict__ kb,
    const u16* __restrict__ vt, u16* __restrict__ yb)
{
  int blk = blockIdx.x;                  // b*512 + h*32 + qt
  int qt = blk & 31, h = (blk >> 5) & 15, b = blk >> 9;
  int w = threadIdx.x >> 6, l = threadIdx.x & 63;
  int lr = l & 15, lg = l >> 4;
  int qbase = qt * 64 + w * 16;
  int sq = qbase + lr;                   // this lane's query row

  const u16* Q  = qb + ((size_t)(b * 16 + h) * 2048) * 64;
  const u16* Kp = kb + ((size_t)(b * 16 + h) * 2048) * 64;
  const u16* Vp = vt + ((size_t)(b * 16 + h) * 64) * 2048;

  // Q B-frags: n = lane&15 (q row), k = lg*8+j (d)
  bf16x8 aq0 = *(const bf16x8*)(Q + (size_t)sq * 64 + lg * 8);
  bf16x8 aq1 = *(const bf16x8*)(Q + (size_t)sq * 64 + 32 + lg * 8);

  f32x4 o[4];
#pragma unroll
  for (int i = 0; i < 4; ++i) o[i] = (f32x4){0.f, 0.f, 0.f, 0.f};
  float mrun = -1e30f, lsum = 0.f;

  int kstart = qbase - 255; if (kstart < 0) kstart = 0;
  kstart &= ~31;
  int kend = qbase + 16;                 // exclusive
  const float scale = 0.125f;
  // K-row permutation: A-matrix row i holds key kt+f(i), f(i)=(i>>2)*8+(i&3)
  // -> acc of sub-mfma0: lane key kt+lg*8+r; sub-mfma1 (+4): kt+lg*8+4+r.
  const int fperm = ((lr >> 2) * 8) + (lr & 3);

  for (int kt = kstart; kt < kend; kt += 32) {
    const u16* k0p = Kp + (size_t)(kt + fperm) * 64;
    const u16* k1p = Kp + (size_t)(kt + fperm + 4) * 64;
    bf16x8 ka0 = *(const bf16x8*)(k0p + lg * 8);
    bf16x8 ka1 = *(const bf16x8*)(k0p + 32 + lg * 8);
    bf16x8 kb0 = *(const bf16x8*)(k1p + lg * 8);
    bf16x8 kb1 = *(const bf16x8*)(k1p + 32 + lg * 8);
    f32x4 s0 = (f32x4){0.f, 0.f, 0.f, 0.f};
    f32x4 s1 = (f32x4){0.f, 0.f, 0.f, 0.f};
    s0 = __builtin_amdgcn_mfma_f32_16x16x32_bf16(ka0, aq0, s0, 0, 0, 0);
    s0 = __builtin_amdgcn_mfma_f32_16x16x32_bf16(ka1, aq1, s0, 0, 0, 0);
    s1 = __builtin_amdgcn_mfma_f32_16x16x32_bf16(kb0, aq0, s1, 0, 0, 0);
    s1 = __builtin_amdgcn_mfma_f32_16x16x32_bf16(kb1, aq1, s1, 0, 0, 0);

    // lane holds keys kt+lg*8+j (j=0..7): j<4 from s0 reg j, else s1 reg j-4
    float p[8];
    float pmax = -1e30f;
#pragma unroll
    for (int j = 0; j < 8; ++j) {
      float sv = (j < 4) ? s0[j] : s1[j - 4];
      int rel = sq - (kt + lg * 8 + j);
      p[j] = (rel >= 0 && rel < 256) ? sv * scale : -1e30f;
      pmax = fmaxf(pmax, p[j]);
    }
    if (!__all(pmax <= mrun + 8.0f)) {    // rare: real max growth (or flush)
      float mx = fmaxf(pmax, __shfl_xor(pmax, 16));
      mx = fmaxf(mx, __shfl_xor(mx, 32));
      float mnew = fmaxf(mrun, mx);
      float f = __expf(mrun - mnew);      // 0 when flushing garbage
      mrun = mnew;
      lsum *= f;
#pragma unroll
      for (int df = 0; df < 4; ++df) o[df] *= f;
    }
    float sumt = 0.f;
#pragma unroll
    for (int j = 0; j < 8; ++j) {
      p[j] = __expf(p[j] - mrun);         // bounded by e^8
      sumt += p[j];
    }
    lsum += sumt;

    // pack P to bf16 in-register: B-frag word j2 = keys (2*j2, 2*j2+1)
    union { u32 wds[4]; bf16x8 v; } pk;
#pragma unroll
    for (int j2 = 0; j2 < 4; ++j2)
      pk.wds[j2] = (u32)f2bf(p[2 * j2]) | ((u32)f2bf(p[2 * j2 + 1]) << 16);

    // PV: A = V^T rows (m = d, k = key), B = pk  ->  O^T[d][s_q]
#pragma unroll
    for (int df = 0; df < 4; ++df) {
      bf16x8 vv = *(const bf16x8*)(Vp + (size_t)(df * 16 + lr) * 2048 + kt + lg * 8);
      o[df] = __builtin_amdgcn_mfma_f32_16x16x32_bf16(vv, pk.v, o[df], 0, 0, 0);
    }
  }

  float sm = lsum;
  sm += __shfl_xor(sm, 16);
  sm += __shfl_xor(sm, 32);
  float inv = 1.f / sm;

  // O^T acc: col = lane&15 = s_q, row = lg*4+reg = d-within-16
  u16* dst = yb + ((size_t)(b * 2048 + sq)) * 1024 + h * 64 + lg * 4;
#pragma unroll
  for (int df = 0; df < 4; ++df) {
    ushort4 pkq;
    pkq.x = f2bf(o[df][0] * inv); pkq.y = f2bf(o[df][1] * inv);
    pkq.z = f2bf(o[df][2] * inv); pkq.w = f2bf(o[df][3] * inv);
    *reinterpret_cast<ushort4*>(dst + df * 16) = pkq;
  }
}

// ---------------------------------------------------------------------------
extern "C" void kernel_launch(void* const* d_in, const int* in_sizes, int n_in,
                              void* d_out, int out_size, void* d_ws, size_t ws_size,
                              hipStream_t stream) {
  const float* x  = (const float*)d_in[0];
  const float* wq = (const float*)d_in[1];
  const float* wk = (const float*)d_in[2];
  const float* wv = (const float*)d_in[3];
  const float* wo = (const float*)d_in[4];

  char* ws = (char*)d_ws;
  const size_t MB = 1u << 20;
  if (ws_size < 49 * MB) return;
  u16*   xb   = (u16*)(ws);                 // 8 MB  x bf16 [4096,1024]
  u16*   wqkv = (u16*)(ws + 8 * MB);        // 6 MB  Wq|Wk|Wv bf16 [3072,1024]
  u16*   wob  = (u16*)(ws + 14 * MB);       // 2 MB  Wo bf16 [1024,1024]
  u16*   qb   = (u16*)(ws + 16 * MB);       // 8 MB  Q bf16 [B,H,S,D] (post-rope)
  u16*   kb   = (u16*)(ws + 24 * MB);       // 8 MB  K bf16 [B,H,S,D] (post-rope)
  u16*   vt   = (u16*)(ws + 32 * MB);       // 8 MB  V^T bf16 [B,H,D,S]
  u16*   yb   = (u16*)(ws + 40 * MB);       // 8 MB  attn out bf16 [B,S,E]
  float* cst  = (float*)(ws + 48 * MB);     // 512 KB interleaved (cos,sin) [S,32,2]
  float* out  = (float*)d_out;

  prep_kernel<<<8448, 256, 0, stream>>>(x, wq, wk, wv, wo, xb, wqkv, wob, cst);
  gemm_qkv<<<192, 512, 0, stream>>>(xb, wqkv, qb, kb, vt, cst);
  attn_kernel<<<1024, 256, 0, stream>>>(qb, kb, vt, yb);
  gemm_out<<<dim3(8, 32), 256, 0, stream>>>(yb, wob, out);
}

// Round 12
// 177.296 us; speedup vs baseline: 1.0211x; 1.0211x over previous
//
#include <hip/hip_runtime.h>
#include <cstdint>
#include <cstddef>

#define AS1 __attribute__((address_space(1)))
#define AS3 __attribute__((address_space(3)))

typedef __attribute__((ext_vector_type(4))) float f32x4;
typedef __attribute__((ext_vector_type(2))) float f32x2;
typedef __attribute__((ext_vector_type(8))) short bf16x8;   // 8 bf16 in 4 VGPRs
typedef unsigned short u16;
typedef unsigned int u32;

#define B_ 2
#define S_ 2048
#define E_ 1024
#define H_ 16
#define D_ 64
#define M_ 4096  /* B_*S_ */

__device__ __forceinline__ u16 f2bf(float f) {
  union { float f; u32 u; } v; v.f = f;
  u32 u = v.u;
  u32 r = (u + 0x7FFFu + ((u >> 16) & 1u)) >> 16;   // RNE
  return (u16)r;
}
__device__ __forceinline__ float bf2f(u16 h) {
  union { u32 u; float f; } v; v.u = ((u32)h) << 16;
  return v.f;
}

__device__ __forceinline__ void gl2lds16(const void* g, void* l) {
  __builtin_amdgcn_global_load_lds((const AS1 void*)g, (AS3 void*)l, 16, 0, 0);
}

// ---------------------------------------------------------------------------
// prep: fp32 -> bf16 conversions (x, Wq|Wk|Wv concat, Wo) + interleaved
// rope (cos,sin) float2 table
// ---------------------------------------------------------------------------
__global__ __launch_bounds__(256) void prep_kernel(
    const float* __restrict__ x, const float* __restrict__ wq,
    const float* __restrict__ wk, const float* __restrict__ wv,
    const float* __restrict__ wo,
    u16* __restrict__ xb, u16* __restrict__ wqkv, u16* __restrict__ wob,
    float* __restrict__ cstab)
{
  int idx = blockIdx.x * 256 + threadIdx.x;
  const int NX4 = (M_ * E_) / 4;          // 1048576 float4s of x
  const int NW4 = (E_ * E_) / 4;          // 262144 per weight
  const int CONV_TOTAL = NX4 + 4 * NW4;   // 2097152
  if (idx < CONV_TOTAL) {
    const float* src; u16* dst; int off;
    if (idx < NX4)                { src = x;  dst = xb;              off = idx; }
    else if (idx < NX4 + NW4)     { src = wq; dst = wqkv;            off = idx - NX4; }
    else if (idx < NX4 + 2 * NW4) { src = wk; dst = wqkv + E_ * E_;  off = idx - NX4 - NW4; }
    else if (idx < NX4 + 3 * NW4) { src = wv; dst = wqkv + 2 * E_ * E_; off = idx - NX4 - 2 * NW4; }
    else                          { src = wo; dst = wob;             off = idx - NX4 - 3 * NW4; }
    float4 v = reinterpret_cast<const float4*>(src)[off];
    ushort4 o;
    o.x = f2bf(v.x); o.y = f2bf(v.y); o.z = f2bf(v.z); o.w = f2bf(v.w);
    reinterpret_cast<ushort4*>(dst)[off] = o;
  } else if (idx < CONV_TOTAL + S_ * 32) {
    int e = idx - CONV_TOTAL;
    int s = e >> 5, i = e & 31;
    double invf = pow(10000.0, -(double)i / 32.0);
    double ang = (double)s * invf;
    cstab[e * 2]     = (float)cos(ang);
    cstab[e * 2 + 1] = (float)sin(ang);
  }
}

// ---------------------------------------------------------------------------
// QKV GEMM, 256x256 tile, BK=64, 8 waves (2M x 4N), 8-phase schedule
// (T2 swizzle + T3/T4 counted vmcnt + T5 setprio), K=1024 -> 8 iterations
// of 2 K-tiles. 2-D XCD swizzle: XCD x owns a 4mt x 6nt sub-grid so its
// L2 working set is A 2MB + B 3MB (was: all 12 nt -> 6MB B thrash).
// Epilogue: in-register RoPE on Q,K + per-wave LDS transpose; V -> V^T.
// ---------------------------------------------------------------------------
#define BARR  asm volatile("s_barrier" ::: "memory")
#define LGKM0 asm volatile("s_waitcnt lgkmcnt(0)" ::: "memory")
#define VMC6  asm volatile("s_waitcnt vmcnt(6)" ::: "memory")
#define VMC0  asm volatile("s_waitcnt vmcnt(0)" ::: "memory")

__global__ __launch_bounds__(512, 2) void gemm_qkv(
    const u16* __restrict__ A, const u16* __restrict__ Bm,
    u16* __restrict__ q_out, u16* __restrict__ k_out, u16* __restrict__ vt_out,
    const float* __restrict__ cstab)
{
  __shared__ __align__(16) u16 lds8[65536];   // 128 KiB
  const int tid = threadIdx.x;
  const int w = tid >> 6, l = tid & 63;
  const int lr = l & 15, lg = l >> 4;
  const int wm = w >> 2, wn = w & 3;

  // 2-D XCD-locality swizzle (bijective): xcd = bid&7 owns 4mt x 6nt
  int bid = blockIdx.x;
  int xcd = bid & 7, i6 = bid >> 3;           // i6 in [0,24)
  int mt = (xcd >> 1) * 4 + i6 / 6;
  int nt = (xcd & 1) * 6 + i6 % 6;

  // staging constants: lane covers row rA(+16*j), 16B chunk (l&3), source
  // k-chunk pre-swizzled so a swizzled ds_read returns logical data.
  const int rA = w * 32 + (l >> 2);
  const int koff = ((l & 3) ^ ((l >> 3) & 3)) * 8;
  const u16* aSrc = A + (size_t)(mt * 256 + rA) * 1024 + koff;
  const u16* bSrc = Bm + (size_t)(nt * 256 + rA) * 1024 + koff;
  const int aswz = 16 * (lg ^ ((lr >> 1) & 3));   // read-side chunk swizzle

#define STG(isB, ks, bb, t) do { \
    const u16* s_ = ((isB) ? bSrc : aSrc) + (t) * 64 + (ks) * 32; \
    u16* d_ = &lds8[(((bb)*2 + (isB))*2 + (ks)) * 8192 + w * 1024]; \
    gl2lds16(s_, d_); \
    gl2lds16(s_ + 16 * 1024, d_ + 512); \
  } while (0)

#define LDA8(qm, ks, bb) do { \
    const char* sl_ = (const char*)lds8 + (((bb)*2)*2 + (ks)) * 16384; \
    _Pragma("unroll") for (int mf_ = 0; mf_ < 4; ++mf_) { \
      int row_ = wm * 128 + (qm) * 64 + mf_ * 16 + lr; \
      av[mf_] = *(const bf16x8*)(sl_ + row_ * 64 + aswz); \
    } } while (0)

#define LDB8(ks, bb) do { \
    const char* sl_ = (const char*)lds8 + (((bb)*2 + 1)*2 + (ks)) * 16384; \
    _Pragma("unroll") for (int nf_ = 0; nf_ < 4; ++nf_) { \
      int row_ = wn * 64 + nf_ * 16 + lr; \
      bv[nf_] = *(const bf16x8*)(sl_ + row_ * 64 + aswz); \
    } } while (0)

#define MMA16(qm) do { \
    __builtin_amdgcn_s_setprio(1); \
    _Pragma("unroll") for (int mf_ = 0; mf_ < 4; ++mf_) \
    _Pragma("unroll") for (int nf_ = 0; nf_ < 4; ++nf_) \
      acc[(qm)*4 + mf_][nf_] = __builtin_amdgcn_mfma_f32_16x16x32_bf16( \
          av[mf_], bv[nf_], acc[(qm)*4 + mf_][nf_], 0, 0, 0); \
    __builtin_amdgcn_s_setprio(0); \
  } while (0)

  f32x4 acc[8][4];
#pragma unroll
  for (int i = 0; i < 8; ++i)
#pragma unroll
    for (int j = 0; j < 4; ++j) acc[i][j] = (f32x4){0.f, 0.f, 0.f, 0.f};
  bf16x8 av[4], bv[4];

  // prologue: K-tile 0 fully + K-tile 1 minus A-K1 (staged at iter0 ph1)
  STG(0, 0, 0, 0); STG(1, 0, 0, 0); STG(0, 1, 0, 0); STG(1, 1, 0, 0);
  STG(1, 0, 1, 1); STG(0, 0, 1, 1); STG(1, 1, 1, 1);
  VMC6; BARR;

  for (int i = 0; i < 8; ++i) {
    // ph1: buf0 K0 qm0 (+B K0)
    LDA8(0, 0, 0); LDB8(0, 0);
    STG(0, 1, 1, 2 * i + 1);
    BARR; LGKM0; MMA16(0); BARR;
    // ph2: buf0 K0 qm1
    LDA8(1, 0, 0);
    if (i < 7) STG(1, 0, 0, 2 * i + 2);
    BARR; LGKM0; MMA16(1); BARR;
    // ph3: buf0 K1 qm0 (+B K1)
    LDA8(0, 1, 0); LDB8(1, 0);
    if (i < 7) STG(0, 0, 0, 2 * i + 2);
    BARR; LGKM0; MMA16(0); BARR;
    // ph4: buf0 K1 qm1
    LDA8(1, 1, 0);
    if (i < 7) STG(1, 1, 0, 2 * i + 2);
    BARR; LGKM0; MMA16(1);
    if (i < 7) { VMC6; } else { VMC0; }
    BARR;
    // ph5: buf1 K0 qm0 (+B K0)
    LDA8(0, 0, 1); LDB8(0, 1);
    if (i < 7) STG(0, 1, 0, 2 * i + 2);
    BARR; LGKM0; MMA16(0); BARR;
    // ph6: buf1 K0 qm1
    LDA8(1, 0, 1);
    if (i < 7) STG(1, 0, 1, 2 * i + 3);
    BARR; LGKM0; MMA16(1); BARR;
    // ph7: buf1 K1 qm0 (+B K1)
    LDA8(0, 1, 1); LDB8(1, 1);
    if (i < 7) STG(0, 0, 1, 2 * i + 3);
    BARR; LGKM0; MMA16(0); BARR;
    // ph8: buf1 K1 qm1
    LDA8(1, 1, 1);
    if (i < 7) STG(1, 1, 1, 2 * i + 3);
    BARR; LGKM0; MMA16(1);
    if (i < 7) VMC6;
    BARR;
  }
  __syncthreads();   // all staging landed (vmcnt(0) at last ph4); LDS reusable

  // ---- epilogue: wave spans rows [stile,+128), cols = one head of one wsel
  int n0 = nt * 256 + wn * 64;
  int wsel = n0 >> 10;
  int hh = (n0 >> 6) & 15;
  int stile = mt * 256 + wm * 128;
  int b = stile >> 11;
  int s0 = stile & 2047;

  if (wsel == 2) {
    // V: transposed scatter [B,H,D,S], ushort4 along s
#pragma unroll
    for (int mf = 0; mf < 8; ++mf) {
      int s = s0 + mf * 16 + lg * 4;
#pragma unroll
      for (int nf = 0; nf < 4; ++nf) {
        int d = nf * 16 + lr;
        ushort4 pk;
        pk.x = f2bf(acc[mf][nf][0]); pk.y = f2bf(acc[mf][nf][1]);
        pk.z = f2bf(acc[mf][nf][2]); pk.w = f2bf(acc[mf][nf][3]);
        *reinterpret_cast<ushort4*>(
            vt_out + ((size_t)(b * 16 + hh) * 64 + d) * 2048 + s) = pk;
      }
    }
  } else {
    // Q/K: RoPE in-register (pair nf, nf+2), per-wave LDS transpose tile
    u16* gout = (wsel == 0 ? q_out : k_out) +
                ((size_t)(b * 16 + hh) * 2048 + s0) * 64;
    u16* lt = &lds8[w * 4352];            // per-wave [64][68] u16
    const f32x2* cst = (const f32x2*)cstab;
#pragma unroll
    for (int P = 0; P < 2; ++P) {         // two 64-row passes
#pragma unroll
      for (int mf_ = 0; mf_ < 4; ++mf_) {
        int mf = P * 4 + mf_;
        int rl = mf_ * 16 + lg * 4;
#pragma unroll
        for (int rr = 0; rr < 4; ++rr) {
          int s = s0 + P * 64 + rl + rr;
#pragma unroll
          for (int nf_ = 0; nf_ < 2; ++nf_) {
            int ii = nf_ * 16 + lr;
            f32x2 cs = cst[s * 32 + ii];
            float a = acc[mf][nf_][rr], b2 = acc[mf][nf_ + 2][rr];
            lt[(rl + rr) * 68 + ii]      = f2bf(a * cs.x - b2 * cs.y);
            lt[(rl + rr) * 68 + 32 + ii] = f2bf(b2 * cs.x + a * cs.y);
          }
        }
      }
      LGKM0;                              // wave-local tile written
      {
        int trl = l >> 3, tcc = l & 7;
#pragma unroll
        for (int it = 0; it < 8; ++it) {
          int row = it * 8 + trl;
          bf16x8 v = *(const bf16x8*)(lt + row * 68 + tcc * 8);
          *(bf16x8*)(gout + (size_t)(P * 64 + row) * 64 + tcc * 8) = v;
        }
      }
      LGKM0;                              // reads done before pass-2 overwrite
    }
  }
#undef STG
#undef LDA8
#undef LDB8
#undef MMA16
}

// ---------------------------------------------------------------------------
// out-projection GEMM (m97 128x128 structure): C[m,n]=sum_k A[m,k]*B[n,k],
// A = attn-out bf16 [4096,1024], B = Wo bf16 [1024,1024], fp32 out.
// 1-D grid 256; XCD x owns mt in [4x,4x+4) x all 8 nt -> per-XCD
// A 1MB + B 2MB, fully L2-resident (A-rows shared by 8 in-XCD blocks).
// ---------------------------------------------------------------------------
__global__ __launch_bounds__(256) void gemm_out(
    const u16* __restrict__ A, const u16* __restrict__ Bm,
    float* __restrict__ f_out)
{
  __shared__ __align__(16) u16 smem[16384];
  u16* lA = smem;
  u16* lB = smem + 8192;
  const int tid = threadIdx.x;
  const int w = tid >> 6, l = tid & 63;
  const int lr = l & 15, lg = l >> 4;
  int bid = blockIdx.x;
  int xcd = bid & 7, i5 = bid >> 3;           // i5 in [0,32)
  const int mt = xcd * 4 + (i5 >> 3);
  const int nt = i5 & 7;
  const int woffm = (w >> 1) * 64, woffn = (w & 1) * 64;

  const int srow = l >> 3;
  const int scol = ((l & 7) ^ srow) * 8;
  const u16* Abase = A + (size_t)(mt * 128) * 1024;
  const u16* Bbase = Bm + (size_t)(nt * 128) * 1024;

  f32x4 acc[4][4];
#pragma unroll
  for (int i = 0; i < 4; ++i)
#pragma unroll
    for (int j = 0; j < 4; ++j) acc[i][j] = (f32x4){0.f, 0.f, 0.f, 0.f};

  for (int kt = 0; kt < 1024; kt += 64) {
    __syncthreads();
#pragma unroll
    for (int i = 0; i < 4; ++i) {
      int ch = w * 4 + i;
      int row = ch * 8 + srow;
      gl2lds16(Abase + row * 1024 + kt + scol, &lA[ch * 512]);
      gl2lds16(Bbase + row * 1024 + kt + scol, &lB[ch * 512]);
    }
    __syncthreads();
#pragma unroll
    for (int kk = 0; kk < 2; ++kk) {
      bf16x8 av[4], bv[4];
#pragma unroll
      for (int mf = 0; mf < 4; ++mf) {
        int row = woffm + mf * 16 + lr;
        int byteoff = row * 128 + ((kk * 64 + lg * 16) ^ ((row & 7) << 4));
        av[mf] = *(const bf16x8*)((const char*)lA + byteoff);
      }
#pragma unroll
      for (int nf = 0; nf < 4; ++nf) {
        int row = woffn + nf * 16 + lr;
        int byteoff = row * 128 + ((kk * 64 + lg * 16) ^ ((row & 7) << 4));
        bv[nf] = *(const bf16x8*)((const char*)lB + byteoff);
      }
#pragma unroll
      for (int mf = 0; mf < 4; ++mf)
#pragma unroll
        for (int nf = 0; nf < 4; ++nf)
          acc[mf][nf] = __builtin_amdgcn_mfma_f32_16x16x32_bf16(
              av[mf], bv[nf], acc[mf][nf], 0, 0, 0);
    }
  }

#pragma unroll
  for (int mf = 0; mf < 4; ++mf) {
    int m = mt * 128 + woffm + mf * 16 + lg * 4;
#pragma unroll
    for (int nf = 0; nf < 4; ++nf) {
      int n = nt * 128 + woffn + nf * 16 + lr;
#pragma unroll
      for (int rr = 0; rr < 4; ++rr)
        f_out[(size_t)(m + rr) * 1024 + n] = acc[mf][nf][rr];
    }
  }
}

// ---------------------------------------------------------------------------
// Banded causal attention, window 256. One wave = 16 query rows (row = lr).
// SWAPPED QK^T (A=K, B=Q) with permuted K-rows -> P in-register as the PV
// B-operand (no LDS/fences/shuffles). XCD swizzle: XCD x owns 4 (b,h)
// pairs -> per-XCD K+V = 2MB, L2-resident.
// ---------------------------------------------------------------------------
__global__ __launch_bounds__(256) void attn_kernel(
    const u16* __restrict__ qb, const u16* __restrict__ kb,
    const u16* __restrict__ vt, u16* __restrict__ yb)
{
  int bid = blockIdx.x;                  // 1024 blocks
  int bh = (bid & 7) | (((bid >> 3) & 3) << 3);   // xcd-local bh set
  int qt = bid >> 5;
  int b = bh >> 4, h = bh & 15;
  int w = threadIdx.x >> 6, l = threadIdx.x & 63;
  int lr = l & 15, lg = l >> 4;
  int qbase = qt * 64 + w * 16;
  int sq = qbase + lr;                   // this lane's query row

  const u16* Q  = qb + ((size_t)(b * 16 + h) * 2048) * 64;
  const u16* Kp = kb + ((size_t)(b * 16 + h) * 2048) * 64;
  const u16* Vp = vt + ((size_t)(b * 16 + h) * 64) * 2048;

  // Q B-frags: n = lane&15 (q row), k = lg*8+j (d)
  bf16x8 aq0 = *(const bf16x8*)(Q + (size_t)sq * 64 + lg * 8);
  bf16x8 aq1 = *(const bf16x8*)(Q + (size_t)sq * 64 + 32 + lg * 8);

  f32x4 o[4];
#pragma unroll
  for (int i = 0; i < 4; ++i) o[i] = (f32x4){0.f, 0.f, 0.f, 0.f};
  float mrun = -1e30f, lsum = 0.f;

  int kstart = qbase - 255; if (kstart < 0) kstart = 0;
  kstart &= ~31;
  int kend = qbase + 16;                 // exclusive
  const float scale = 0.125f;
  // K-row permutation: A-matrix row i holds key kt+f(i), f(i)=(i>>2)*8+(i&3)
  const int fperm = ((lr >> 2) * 8) + (lr & 3);

  for (int kt = kstart; kt < kend; kt += 32) {
    const u16* k0p = Kp + (size_t)(kt + fperm) * 64;
    const u16* k1p = Kp + (size_t)(kt + fperm + 4) * 64;
    bf16x8 ka0 = *(const bf16x8*)(k0p + lg * 8);
    bf16x8 ka1 = *(const bf16x8*)(k0p + 32 + lg * 8);
    bf16x8 kb0 = *(const bf16x8*)(k1p + lg * 8);
    bf16x8 kb1 = *(const bf16x8*)(k1p + 32 + lg * 8);
    f32x4 s0 = (f32x4){0.f, 0.f, 0.f, 0.f};
    f32x4 s1 = (f32x4){0.f, 0.f, 0.f, 0.f};
    s0 = __builtin_amdgcn_mfma_f32_16x16x32_bf16(ka0, aq0, s0, 0, 0, 0);
    s0 = __builtin_amdgcn_mfma_f32_16x16x32_bf16(ka1, aq1, s0, 0, 0, 0);
    s1 = __builtin_amdgcn_mfma_f32_16x16x32_bf16(kb0, aq0, s1, 0, 0, 0);
    s1 = __builtin_amdgcn_mfma_f32_16x16x32_bf16(kb1, aq1, s1, 0, 0, 0);

    // lane holds keys kt+lg*8+j (j=0..7): j<4 from s0 reg j, else s1 reg j-4
    float p[8];
    float pmax = -1e30f;
#pragma unroll
    for (int j = 0; j < 8; ++j) {
      float sv = (j < 4) ? s0[j] : s1[j - 4];
      int rel = sq - (kt + lg * 8 + j);
      p[j] = (rel >= 0 && rel < 256) ? sv * scale : -1e30f;
      pmax = fmaxf(pmax, p[j]);
    }
    if (!__all(pmax <= mrun + 8.0f)) {    // rare: real max growth (or flush)
      float mx = fmaxf(pmax, __shfl_xor(pmax, 16));
      mx = fmaxf(mx, __shfl_xor(mx, 32));
      float mnew = fmaxf(mrun, mx);
      float f = __expf(mrun - mnew);      // 0 when flushing garbage
      mrun = mnew;
      lsum *= f;
#pragma unroll
      for (int df = 0; df < 4; ++df) o[df] *= f;
    }
    float sumt = 0.f;
#pragma unroll
    for (int j = 0; j < 8; ++j) {
      p[j] = __expf(p[j] - mrun);         // bounded by e^8
      sumt += p[j];
    }
    lsum += sumt;

    // pack P to bf16 in-register: B-frag word j2 = keys (2*j2, 2*j2+1)
    union { u32 wds[4]; bf16x8 v; } pk;
#pragma unroll
    for (int j2 = 0; j2 < 4; ++j2)
      pk.wds[j2] = (u32)f2bf(p[2 * j2]) | ((u32)f2bf(p[2 * j2 + 1]) << 16);

    // PV: A = V^T rows (m = d, k = key), B = pk  ->  O^T[d][s_q]
#pragma unroll
    for (int df = 0; df < 4; ++df) {
      bf16x8 vv = *(const bf16x8*)(Vp + (size_t)(df * 16 + lr) * 2048 + kt + lg * 8);
      o[df] = __builtin_amdgcn_mfma_f32_16x16x32_bf16(vv, pk.v, o[df], 0, 0, 0);
    }
  }

  float sm = lsum;
  sm += __shfl_xor(sm, 16);
  sm += __shfl_xor(sm, 32);
  float inv = 1.f / sm;

  // O^T acc: col = lane&15 = s_q, row = lg*4+reg = d-within-16
  u16* dst = yb + ((size_t)(b * 2048 + sq)) * 1024 + h * 64 + lg * 4;
#pragma unroll
  for (int df = 0; df < 4; ++df) {
    ushort4 pkq;
    pkq.x = f2bf(o[df][0] * inv); pkq.y = f2bf(o[df][1] * inv);
    pkq.z = f2bf(o[df][2] * inv); pkq.w = f2bf(o[df][3] * inv);
    *reinterpret_cast<ushort4*>(dst + df * 16) = pkq;
  }
}

// ---------------------------------------------------------------------------
extern "C" void kernel_launch(void* const* d_in, const int* in_sizes, int n_in,
                              void* d_out, int out_size, void* d_ws, size_t ws_size,
                              hipStream_t stream) {
  const float* x  = (const float*)d_in[0];
  const float* wq = (const float*)d_in[1];
  const float* wk = (const float*)d_in[2];
  const float* wv = (const float*)d_in[3];
  const float* wo = (const float*)d_in[4];

  char* ws = (char*)d_ws;
  const size_t MB = 1u << 20;
  if (ws_size < 49 * MB) return;
  u16*   xb   = (u16*)(ws);                 // 8 MB  x bf16 [4096,1024]
  u16*   wqkv = (u16*)(ws + 8 * MB);        // 6 MB  Wq|Wk|Wv bf16 [3072,1024]
  u16*   wob  = (u16*)(ws + 14 * MB);       // 2 MB  Wo bf16 [1024,1024]
  u16*   qb   = (u16*)(ws + 16 * MB);       // 8 MB  Q bf16 [B,H,S,D] (post-rope)
  u16*   kb   = (u16*)(ws + 24 * MB);       // 8 MB  K bf16 [B,H,S,D] (post-rope)
  u16*   vt   = (u16*)(ws + 32 * MB);       // 8 MB  V^T bf16 [B,H,D,S]
  u16*   yb   = (u16*)(ws + 40 * MB);       // 8 MB  attn out bf16 [B,S,E]
  float* cst  = (float*)(ws + 48 * MB);     // 512 KB interleaved (cos,sin) [S,32,2]
  float* out  = (float*)d_out;

  prep_kernel<<<8448, 256, 0, stream>>>(x, wq, wk, wv, wo, xb, wqkv, wob, cst);
  gemm_qkv<<<192, 512, 0, stream>>>(xb, wqkv, qb, kb, vt, cst);
  attn_kernel<<<1024, 256, 0, stream>>>(qb, kb, vt, yb);
  gemm_out<<<256, 256, 0, stream>>>(yb, wob, out);
}